// Round 13
// baseline (96.514 us; speedup 1.0000x reference)
//
#include <hip/hip_runtime.h>
#include <hip/hip_bf16.h>
#include <hip/hip_fp16.h>

#define NB 2
#define ND 1024
#define NL 4096
#define NFS 4
#define NDEPTH 11
#define LN_EPS 1e-5f

#define BM 128
#define BN 128
#define BK 32
#define NKI (ND / BK)
#define ASZ (BM * BK)  // shorts per A (or B) buffer

#define CPAD 3072          // f16 elements of zero pad (lev10 reads back 3*1024)
#define CBUF (CPAD + NL)   // 7168 f16 = 14336 B per buffer

typedef __bf16 bf16x8 __attribute__((ext_vector_type(8)));
typedef float f32x4 __attribute__((ext_vector_type(4)));
typedef _Float16 half8 __attribute__((ext_vector_type(8)));
typedef unsigned short ushort8 __attribute__((ext_vector_type(8)));

__device__ __forceinline__ unsigned short f2bf(float f) {
    __hip_bfloat16 h = __float2bfloat16(f);
    unsigned short u;
    __builtin_memcpy(&u, &h, 2);
    return u;
}

__device__ __forceinline__ float bf2f(unsigned short u) {
    unsigned int ui = (unsigned int)u << 16;
    float f;
    __builtin_memcpy(&f, &ui, 4);
    return f;
}

__device__ __forceinline__ unsigned int pack2bf(float lo, float hi) {
    return (unsigned int)f2bf(lo) | ((unsigned int)f2bf(hi) << 16);
}

// async global->LDS, 16B per lane (wave-uniform LDS base + lane*16)
__device__ __forceinline__ void llds16(const void* g, void* l) {
    __builtin_amdgcn_global_load_lds(
        (const __attribute__((address_space(1))) unsigned int*)g,
        (__attribute__((address_space(3))) unsigned int*)l, 16, 0, 0);
}

__device__ __forceinline__ half8 ldx8(const float* p) {
    const float4 v0 = *reinterpret_cast<const float4*>(p);
    const float4 v1 = *reinterpret_cast<const float4*>(p + 4);
    half8 r;
    r[0] = (_Float16)v0.x; r[1] = (_Float16)v0.y;
    r[2] = (_Float16)v0.z; r[3] = (_Float16)v0.w;
    r[4] = (_Float16)v1.x; r[5] = (_Float16)v1.y;
    r[6] = (_Float16)v1.z; r[7] = (_Float16)v1.w;
    return r;
}

// zero-clamped block load: valid address always, result zeroed if off<0
__device__ __forceinline__ half8 ldx8z(const float* xrow, int off) {
    half8 v = ldx8(xrow + (off >= 0 ? off : 0));
    return (off >= 0) ? v : (half8)0;
}

// ---------------------------------------------------------------- K0: W -> bf16
__global__ __launch_bounds__(256) void wconv_kernel(const float* __restrict__ w,
                                                    unsigned short* __restrict__ wbf) {
    const int idx8 = (blockIdx.x * 256 + threadIdx.x) * 8;
    const float4 v0 = *reinterpret_cast<const float4*>(w + idx8);
    const float4 v1 = *reinterpret_cast<const float4*>(w + idx8 + 4);
    uint4 o;
    o.x = pack2bf(v0.x, v0.y);
    o.y = pack2bf(v0.z, v0.w);
    o.z = pack2bf(v1.x, v1.y);
    o.w = pack2bf(v1.z, v1.w);
    *reinterpret_cast<uint4*>(wbf + idx8) = o;
}

// ------------------------------------------------- K1: dilated conv cascade + gating
// 512 threads; thread t owns [t*8, t*8+8) as half8. Levels 0-2 register-only (R12).
// Levels 3-8 are computed in PAIRS (one barrier per 2 levels): thread reads 9 aligned
// taps of a^{L-1}, redundantly computes a^L at offsets 0,-2d,-4d,-6d in registers,
// derives a^{L+1} + both gates, writes only a^{L+1}. Lev 9 solo round, lev 10 tail.
// Barriers: 8 -> 5. Gate fully f16-packed.
__global__ __launch_bounds__(512) void conv_cascade_kernel(const float* __restrict__ x,
                                                           const float* __restrict__ h0,
                                                           const float* __restrict__ h1,
                                                           unsigned short* __restrict__ ybf) {
    __shared__ _Float16 a_sh[2][CBUF];  // 28672 B
    const int row = blockIdx.x;         // b*ND + d
    const int d = row & (ND - 1);
    const int t = threadIdx.x;

    // zero both pads (never written again)
    if (t < CPAD / 8) {
        *reinterpret_cast<half8*>(&a_sh[0][t * 8]) = (half8)0;
        *reinterpret_cast<half8*>(&a_sh[1][t * 8]) = (half8)0;
    }

    const float* xrow = x + (size_t)row * NL;

    _Float16 h0c[NFS], h1c[NFS];
#pragma unroll
    for (int k = 0; k < NFS; ++k) {
        h0c[k] = (_Float16)h0[d * NFS + k];
        h1c[k] = (_Float16)h1[d * NFS + k];
    }

    const int l8 = t * 8;
    const int A = CPAD + l8;

    // x window: [l8-32, l8+8) as 5 half8 blocks (zero-clamped at row start)
    const half8 X0 = ldx8z(xrow, l8 - 32);
    const half8 X1 = ldx8z(xrow, l8 - 24);
    const half8 X2 = ldx8z(xrow, l8 - 16);
    const half8 X3 = ldx8z(xrow, l8 - 8);
    const half8 C  = ldx8(xrow + l8);

    const __half2 nlog2e = __float2half2_rn(-1.44269504f);
    const __half2 one2 = __float2half2_rn(1.f);
    const __half2 two2 = __float2half2_rn(2.f);
    __half2 yacc2[4];
#pragma unroll
    for (int p = 0; p < 4; ++p) yacc2[p] = __float2half2_rn(0.f);

#define SH1(L, R) __builtin_shufflevector(L, R, 7, 8, 9, 10, 11, 12, 13, 14)
#define SH2(L, R) __builtin_shufflevector(L, R, 6, 7, 8, 9, 10, 11, 12, 13)
#define SH3(L, R) __builtin_shufflevector(L, R, 5, 6, 7, 8, 9, 10, 11, 12)
#define SH4(L, R) __builtin_shufflevector(L, R, 4, 5, 6, 7, 8, 9, 10, 11)
#define SH6(L, R) __builtin_shufflevector(L, R, 2, 3, 4, 5, 6, 7, 8, 9)
#define CONV_D1(L, R, hc) ((R)*hc[3] + SH1(L, R) * hc[2] + SH2(L, R) * hc[1] + SH3(L, R) * hc[0])
#define CONV_D2(L, R, hc) ((R)*hc[3] + SH2(L, R) * hc[2] + SH4(L, R) * hc[1] + SH6(L, R) * hc[0])

#define GATE(av, bv, SC2)                                           \
    {                                                               \
        __half2 ap_[4], bp_[4];                                     \
        __builtin_memcpy(ap_, &(av), 16);                           \
        __builtin_memcpy(bp_, &(bv), 16);                           \
        _Pragma("unroll") for (int p = 0; p < 4; ++p) {             \
            const __half2 e = h2exp2(__hmul2(ap_[p], nlog2e));      \
            const __half2 s = h2rcp(__hadd2(e, one2));              \
            const __half2 g = __hmul2(__hmul2(s, bp_[p]), SC2);     \
            yacc2[p] = __hadd2(g, yacc2[p]);                        \
        }                                                           \
    }

    // ---- lev 0 (dil=1), register-only
    const half8 a0_1 = CONV_D1(X0, X1, h0c);
    const half8 a0_2 = CONV_D1(X1, X2, h0c);
    const half8 a0_3 = CONV_D1(X2, X3, h0c);
    const half8 a0_4 = CONV_D1(X3, C, h0c);
    const half8 b0 = CONV_D1(X3, C, h1c);

    // ---- lev 1 (dil=2), register-only; gate x2
    const half8 a1_2 = CONV_D2(a0_1, a0_2, h0c);
    const half8 a1_3 = CONV_D2(a0_2, a0_3, h0c);
    const half8 a1_4 = CONV_D2(a0_3, a0_4, h0c);
    const half8 b1 = CONV_D2(a0_3, a0_4, h1c);
    GATE(a1_4, b0, two2)

    // ---- lev 2 (dil=4), register-only; gate
    const half8 s4 = SH4(a1_3, a1_4);
    const half8 s12 = SH4(a1_2, a1_3);
    const half8 a2 = a1_4 * h0c[3] + s4 * h0c[2] + a1_3 * h0c[1] + s12 * h0c[0];
    const half8 b2 = a1_4 * h1c[3] + s4 * h1c[2] + a1_3 * h1c[1] + s12 * h1c[0];
    GATE(a2, b1, one2)

    half8 cur = a2;
    half8 bprev = b2;
    _Float16* rbp = &a_sh[0][0];
    _Float16* wbp = &a_sh[1][0];
    *reinterpret_cast<half8*>(&rbp[A]) = cur;  // publish a2
    __syncthreads();

    // paired round for levels (L, L+1), d = dil(L); one barrier per pair.
    // reads a^{L-1} taps m*d (m=1..9), computes a^L at 0,-2d,-4d,-6d in regs,
    // gates L and L+1, writes only a^{L+1}.
#define PAIR(DD)                                                                     \
    {                                                                                \
        const half8 t1 = *reinterpret_cast<const half8*>(&rbp[A - (DD)]);            \
        const half8 t2 = *reinterpret_cast<const half8*>(&rbp[A - 2 * (DD)]);        \
        const half8 t3 = *reinterpret_cast<const half8*>(&rbp[A - 3 * (DD)]);        \
        const half8 t4 = *reinterpret_cast<const half8*>(&rbp[A - 4 * (DD)]);        \
        const half8 t5 = *reinterpret_cast<const half8*>(&rbp[A - 5 * (DD)]);        \
        const half8 t6 = *reinterpret_cast<const half8*>(&rbp[A - 6 * (DD)]);        \
        const half8 t7 = *reinterpret_cast<const half8*>(&rbp[A - 7 * (DD)]);        \
        const half8 t8 = *reinterpret_cast<const half8*>(&rbp[A - 8 * (DD)]);        \
        const half8 t9 = *reinterpret_cast<const half8*>(&rbp[A - 9 * (DD)]);        \
        const half8 aL0 = cur * h0c[3] + t1 * h0c[2] + t2 * h0c[1] + t3 * h0c[0];    \
        const half8 aL2 = t2 * h0c[3] + t3 * h0c[2] + t4 * h0c[1] + t5 * h0c[0];     \
        const half8 aL4 = t4 * h0c[3] + t5 * h0c[2] + t6 * h0c[1] + t7 * h0c[0];     \
        const half8 aL6 = t6 * h0c[3] + t7 * h0c[2] + t8 * h0c[1] + t9 * h0c[0];     \
        const half8 bL0 = cur * h1c[3] + t1 * h1c[2] + t2 * h1c[1] + t3 * h1c[0];    \
        GATE(aL0, bprev, one2)                                                       \
        const half8 aN = aL0 * h0c[3] + aL2 * h0c[2] + aL4 * h0c[1] + aL6 * h0c[0];  \
        const half8 bN = aL0 * h1c[3] + aL2 * h1c[2] + aL4 * h1c[1] + aL6 * h1c[0];  \
        GATE(aN, bL0, one2)                                                          \
        *reinterpret_cast<half8*>(&wbp[A]) = aN;                                     \
        cur = aN;                                                                    \
        bprev = bN;                                                                  \
        { _Float16* tmpp = rbp; rbp = wbp; wbp = tmpp; }                             \
        __syncthreads();                                                             \
    }

    PAIR(8)     // levels 3,4   (dil 8,16)
    PAIR(32)    // levels 5,6   (dil 32,64)
    PAIR(128)   // levels 7,8   (dil 128,256)

    // ---- lev 9 (dil=512) solo round
    {
        const half8 a1v = *reinterpret_cast<const half8*>(&rbp[A - 512]);
        const half8 a2v = *reinterpret_cast<const half8*>(&rbp[A - 1024]);
        const half8 a3v = *reinterpret_cast<const half8*>(&rbp[A - 1536]);
        const half8 an = cur * h0c[3] + a1v * h0c[2] + a2v * h0c[1] + a3v * h0c[0];
        const half8 bn = cur * h1c[3] + a1v * h1c[2] + a2v * h1c[1] + a3v * h1c[0];
        GATE(an, bprev, one2)
        *reinterpret_cast<half8*>(&wbp[A]) = an;
        cur = an;
        bprev = bn;
        { _Float16* tmpp = rbp; rbp = wbp; wbp = tmpp; }
        __syncthreads();
    }

    // ---- lev 10 (dil=1024): a-conv only (b_list[10] dead), no write-back
    {
        const half8 a1v = *reinterpret_cast<const half8*>(&rbp[A - 1024]);
        const half8 a2v = *reinterpret_cast<const half8*>(&rbp[A - 2048]);
        const half8 a3v = *reinterpret_cast<const half8*>(&rbp[A - 3072]);
        const half8 an = cur * h0c[3] + a1v * h0c[2] + a2v * h0c[1] + a3v * h0c[0];
        GATE(an, bprev, one2)
    }
#undef PAIR
#undef CMATH
#undef GATE
#undef CONV_D1
#undef CONV_D2
#undef SH1
#undef SH2
#undef SH3
#undef SH4
#undef SH6

    const float2 f0 = __half22float2(yacc2[0]);
    const float2 f1 = __half22float2(yacc2[1]);
    const float2 f2 = __half22float2(yacc2[2]);
    const float2 f3 = __half22float2(yacc2[3]);
    uint4 o;
    o.x = pack2bf(f0.x, f0.y);
    o.y = pack2bf(f1.x, f1.y);
    o.z = pack2bf(f2.x, f2.y);
    o.w = pack2bf(f3.x, f3.y);
    *reinterpret_cast<uint4*>(ybf + (size_t)row * NL + t * 8) = o;
}

// ------------------------------------------- K2: y [b][c][l] bf16 -> yT [b][l][c] bf16
// ushort8-vectorized both directions; XOR-swizzled LDS (blk ^= ((row>>3)^row)&7)
// keeps BOTH the b128 writes and the per-column reads bank-conflict-free.
__global__ __launch_bounds__(256) void transpose_kernel(const unsigned short* __restrict__ ybf,
                                                        unsigned short* __restrict__ yT) {
    __shared__ unsigned short tile[64 * 64];
    const int l0 = blockIdx.x * 64;
    const int c0 = blockIdx.y * 64;
    const int b = blockIdx.z;
    const int t = threadIdx.x;

    const int li8 = (t & 7) * 8;   // load: 8 l-cols
    const int ci_ = t >> 3;        // load: c-row (0..31), +32 second pass
#pragma unroll
    for (int p = 0; p < 2; ++p) {
        const int ci = ci_ + p * 32;
        const ushort8 v = *reinterpret_cast<const ushort8*>(
            ybf + (size_t)(b * ND + c0 + ci) * NL + l0 + li8);
        const int blk = ((li8 >> 3) ^ ((ci >> 3) ^ ci)) & 7;
        *reinterpret_cast<ushort8*>(&tile[ci * 64 + blk * 8]) = v;
    }
    __syncthreads();

    const int li_ = t >> 3;        // store: l-row (0..31), +32 second pass
    const int cv8 = (t & 7) * 8;   // store: 8 c-cols
#pragma unroll
    for (int p = 0; p < 2; ++p) {
        const int li = li_ + p * 32;
        ushort8 o;
#pragma unroll
        for (int j = 0; j < 8; ++j) {
            const int r = cv8 + j;
            const int blk = ((li >> 3) ^ ((r >> 3) ^ r)) & 7;
            o[j] = tile[r * 64 + blk * 8 + (li & 7)];
        }
        *reinterpret_cast<ushort8*>(yT + ((size_t)b * NL + l0 + li) * ND + c0 + cv8) = o;
    }
}

// --------------------------- K3: mixed[b][o][l] = bf16( (W @ y)[o][l] + b_mix[o] )
// ring-3 LDS staging, counted vmcnt(4); XCD-chunked block swizzle.
__global__ __launch_bounds__(256) void gemm_kernel(const unsigned short* __restrict__ wbf,
                                                   const unsigned short* __restrict__ yT,
                                                   const float* __restrict__ bmix,
                                                   unsigned short* __restrict__ mixed) {
    __shared__ unsigned short As[3][BM][BK];  // 24 KiB
    __shared__ unsigned short Bs[3][BN][BK];  // 24 KiB

    // XCD swizzle: 512 blocks, 8 XCDs, 64 per XCD (512%8==0 -> bijective)
    const int orig = blockIdx.x;
    const int wgid = (orig & 7) * 64 + (orig >> 3);
    const int b = wgid & 1;
    const int m0 = ((wgid >> 1) & 7) * BM;
    const int n0 = (wgid >> 4) * BN;

    const int t = threadIdx.x;
    const int lane = t & 63, wid = t >> 6;
    const int wr = wid >> 1, wc = wid & 1;  // 2x2 waves, each 64x64
    const int fr = lane & 15;
    const int fk = (lane >> 4) * 8;

    const int srow = wid * 32 + (lane >> 2);
    const int sk = (lane & 3) * 8;
    const unsigned short* Ag = wbf + (size_t)(m0 + srow) * ND + sk;
    const unsigned short* Bg = yT + ((size_t)b * NL + n0 + srow) * ND + sk;
    unsigned short* A0 = &As[0][0][0];
    unsigned short* B0 = &Bs[0][0][0];
    unsigned short* AsW = A0 + wid * 32 * BK;
    unsigned short* BsW = B0 + wid * 32 * BK;

#define STAGE(bo, kt)                           \
    llds16(Ag + (kt), AsW + (bo));              \
    llds16(Ag + (kt) + 16 * ND, AsW + (bo) + 16 * BK); \
    llds16(Bg + (kt), BsW + (bo));              \
    llds16(Bg + (kt) + 16 * ND, BsW + (bo) + 16 * BK);

    f32x4 acc[4][4];
#pragma unroll
    for (int mi = 0; mi < 4; ++mi)
#pragma unroll
        for (int ni = 0; ni < 4; ++ni)
            acc[mi][ni] = (f32x4){0.f, 0.f, 0.f, 0.f};

    // prologue: stage tiles 0,1 into bufs 0,1 (8 loads outstanding)
    STAGE(0, 0)
    STAGE(ASZ, BK)

    int bc = 0;   // compute buffer index
    int bs = 2;   // stage buffer index
#pragma unroll 1
    for (int ki = 0; ki < NKI; ++ki) {
        if (ki + 1 < NKI) {
            asm volatile("s_waitcnt vmcnt(4)" ::: "memory");  // tile ki landed
        } else {
            asm volatile("s_waitcnt vmcnt(0)" ::: "memory");
        }
        __builtin_amdgcn_s_barrier();
        __builtin_amdgcn_sched_barrier(0);

        if (ki + 2 < NKI) {
            const int bo = bs * ASZ;
            const int kt = (ki + 2) * BK;
            STAGE(bo, kt)
        }

        const int bco = bc * ASZ;
        bf16x8 af[4], bv[4];
#pragma unroll
        for (int mi = 0; mi < 4; ++mi)
            af[mi] = *reinterpret_cast<const bf16x8*>(A0 + bco + (wr * 64 + mi * 16 + fr) * BK + fk);
#pragma unroll
        for (int ni = 0; ni < 4; ++ni)
            bv[ni] = *reinterpret_cast<const bf16x8*>(B0 + bco + (wc * 64 + ni * 16 + fr) * BK + fk);
#pragma unroll
        for (int mi = 0; mi < 4; ++mi)
#pragma unroll
            for (int ni = 0; ni < 4; ++ni)
                acc[mi][ni] = __builtin_amdgcn_mfma_f32_16x16x32_bf16(af[mi], bv[ni],
                                                                      acc[mi][ni], 0, 0, 0);
        bc = (bc == 2) ? 0 : bc + 1;
        bs = (bs == 2) ? 0 : bs + 1;
    }
#undef STAGE

    // epilogue: D[row][col], col = lane&15, row = (lane>>4)*4 + r
    const size_t bbase = (size_t)b * ND * NL;
#pragma unroll
    for (int mi = 0; mi < 4; ++mi) {
#pragma unroll
        for (int r = 0; r < 4; ++r) {
            const int o = m0 + wr * 64 + mi * 16 + (lane >> 4) * 4 + r;
            const float bm = bmix[o];
            const size_t rowbase = bbase + (size_t)o * NL;
#pragma unroll
            for (int ni = 0; ni < 4; ++ni) {
                const int l = n0 + wc * 64 + ni * 16 + fr;
                mixed[rowbase + l] = f2bf(acc[mi][ni][r] + bm);
            }
        }
    }
}

// ------------------------- K4: z = mixed + x (regs) -> LayerNorm over channels -> out
// 1024 threads (16 waves) per block: 32 l-cols x 32 c-groups, zv[32] in registers.
__global__ __launch_bounds__(1024) void ln_kernel(const unsigned short* __restrict__ mixed,
                                                  const float* __restrict__ x,
                                                  const float* __restrict__ gamma,
                                                  const float* __restrict__ beta,
                                                  float* __restrict__ out) {
    __shared__ float gsh[ND], bsh[ND];           // 8 KiB
    __shared__ float sred[32][33], qred[32][33]; // 8.25 KiB
    __shared__ float mu_s[32], rs_s[32];

    const int t = threadIdx.x;
    gsh[t] = gamma[t];
    bsh[t] = beta[t];

    const int b = blockIdx.y;
    const int l0 = blockIdx.x * 32;
    const int tl = t & 31, tg = t >> 5;  // 32 c-groups x 32 cols
    const size_t base = (size_t)b * ND * NL + l0 + tl;

    float zv[32];
    float s = 0.f, q = 0.f;
#pragma unroll
    for (int j = 0; j < 32; ++j) {
        const size_t idx = base + (size_t)(tg + j * 32) * NL;
        const float v = bf2f(mixed[idx]) + x[idx];
        zv[j] = v;
        s += v;
        q += v * v;
    }

    sred[tg][tl] = s;
    qred[tg][tl] = q;
    __syncthreads();  // also covers gsh/bsh writes
    if (tg == 0) {
        float S = 0.f, Q = 0.f;
#pragma unroll
        for (int g = 0; g < 32; ++g) {
            S += sred[g][tl];
            Q += qred[g][tl];
        }
        const float mu = S * (1.f / ND);
        const float var = Q * (1.f / ND) - mu * mu;
        mu_s[tl] = mu;
        rs_s[tl] = rsqrtf(var + LN_EPS);
    }
    __syncthreads();
    const float mu = mu_s[tl], rs = rs_s[tl];
#pragma unroll
    for (int j = 0; j < 32; ++j) {
        const int c = tg + j * 32;
        out[base + (size_t)c * NL] = (zv[j] - mu) * rs * gsh[c] + bsh[c];
    }
}

extern "C" void kernel_launch(void* const* d_in, const int* in_sizes, int n_in,
                              void* d_out, int out_size, void* d_ws, size_t ws_size,
                              hipStream_t stream) {
    (void)in_sizes; (void)n_in; (void)out_size; (void)ws_size;
    const float* x = (const float*)d_in[0];
    const float* h0 = (const float*)d_in[1];
    const float* h1 = (const float*)d_in[2];
    const float* wmix = (const float*)d_in[3];
    const float* bmix = (const float*)d_in[4];
    const float* gamma = (const float*)d_in[5];
    const float* beta = (const float*)d_in[6];
    float* out = (float*)d_out;

    char* ws = (char*)d_ws;
    unsigned short* ybf = (unsigned short*)(ws);                              // 16 MiB
    unsigned short* yT = (unsigned short*)(ws + (size_t)16 * 1024 * 1024);    // 16 MiB
    unsigned short* wbf = (unsigned short*)(ws + (size_t)32 * 1024 * 1024);   // 2 MiB
    unsigned short* mixed = (unsigned short*)(ws + (size_t)34 * 1024 * 1024); // 16 MiB

    wconv_kernel<<<dim3(ND * ND / (256 * 8)), 256, 0, stream>>>(wmix, wbf);
    conv_cascade_kernel<<<dim3(NB * ND), 512, 0, stream>>>(x, h0, h1, ybf);
    transpose_kernel<<<dim3(NL / 64, ND / 64, NB), 256, 0, stream>>>(ybf, yT);
    gemm_kernel<<<dim3(512), 256, 0, stream>>>(wbf, yT, bmix, mixed);
    ln_kernel<<<dim3(NL / 32, NB), 1024, 0, stream>>>(mixed, x, gamma, beta, out);
}

// Round 14
// 93.812 us; speedup vs baseline: 1.0288x; 1.0288x over previous
//
#include <hip/hip_runtime.h>
#include <hip/hip_bf16.h>
#include <hip/hip_fp16.h>

#define NB 2
#define ND 1024
#define NL 4096
#define NFS 4
#define NDEPTH 11
#define LN_EPS 1e-5f

#define BM 128
#define BN 128
#define BK 32
#define NKI (ND / BK)
#define ASZ (BM * BK)  // shorts per A (or B) buffer

#define CPAD 3072          // f16 elements of zero pad (lev10 reads back 3*1024)
#define CBUF (CPAD + NL)   // 7168 f16 = 14336 B per buffer

typedef __bf16 bf16x8 __attribute__((ext_vector_type(8)));
typedef float f32x4 __attribute__((ext_vector_type(4)));
typedef _Float16 half8 __attribute__((ext_vector_type(8)));
typedef unsigned short ushort8 __attribute__((ext_vector_type(8)));

__device__ __forceinline__ unsigned short f2bf(float f) {
    __hip_bfloat16 h = __float2bfloat16(f);
    unsigned short u;
    __builtin_memcpy(&u, &h, 2);
    return u;
}

__device__ __forceinline__ float bf2f(unsigned short u) {
    unsigned int ui = (unsigned int)u << 16;
    float f;
    __builtin_memcpy(&f, &ui, 4);
    return f;
}

__device__ __forceinline__ unsigned int pack2bf(float lo, float hi) {
    return (unsigned int)f2bf(lo) | ((unsigned int)f2bf(hi) << 16);
}

// async global->LDS, 16B per lane (wave-uniform LDS base + lane*16)
__device__ __forceinline__ void llds16(const void* g, void* l) {
    __builtin_amdgcn_global_load_lds(
        (const __attribute__((address_space(1))) unsigned int*)g,
        (__attribute__((address_space(3))) unsigned int*)l, 16, 0, 0);
}

__device__ __forceinline__ half8 ldx8(const float* p) {
    const float4 v0 = *reinterpret_cast<const float4*>(p);
    const float4 v1 = *reinterpret_cast<const float4*>(p + 4);
    half8 r;
    r[0] = (_Float16)v0.x; r[1] = (_Float16)v0.y;
    r[2] = (_Float16)v0.z; r[3] = (_Float16)v0.w;
    r[4] = (_Float16)v1.x; r[5] = (_Float16)v1.y;
    r[6] = (_Float16)v1.z; r[7] = (_Float16)v1.w;
    return r;
}

// zero-clamped block load: valid address always, result zeroed if off<0
__device__ __forceinline__ half8 ldx8z(const float* xrow, int off) {
    half8 v = ldx8(xrow + (off >= 0 ? off : 0));
    return (off >= 0) ? v : (half8)0;
}

// ---------------------------------------------------------------- K0: W -> bf16
__global__ __launch_bounds__(256) void wconv_kernel(const float* __restrict__ w,
                                                    unsigned short* __restrict__ wbf) {
    const int idx8 = (blockIdx.x * 256 + threadIdx.x) * 8;
    const float4 v0 = *reinterpret_cast<const float4*>(w + idx8);
    const float4 v1 = *reinterpret_cast<const float4*>(w + idx8 + 4);
    uint4 o;
    o.x = pack2bf(v0.x, v0.y);
    o.y = pack2bf(v0.z, v0.w);
    o.z = pack2bf(v1.x, v1.y);
    o.w = pack2bf(v1.z, v1.w);
    *reinterpret_cast<uint4*>(wbf + idx8) = o;
}

// ------------------------------------------------- K1: dilated conv cascade + gating
// R12-exact structure (best measured: 39.5 us). 512 threads; thread t owns
// [t*8, t*8+8) as half8. Levels 0-2 (dil 1/2/4) register-only from a redundant
// x-window; levels 3-9 via double-buffered f16 LDS (1 barrier/level); lev 10
// a-conv only. Gate fully f16-packed (h2exp2/h2rcp).
__global__ __launch_bounds__(512) void conv_cascade_kernel(const float* __restrict__ x,
                                                           const float* __restrict__ h0,
                                                           const float* __restrict__ h1,
                                                           unsigned short* __restrict__ ybf) {
    __shared__ _Float16 a_sh[2][CBUF];  // 28672 B
    const int row = blockIdx.x;         // b*ND + d
    const int d = row & (ND - 1);
    const int t = threadIdx.x;

    // zero both pads (never written again)
    if (t < CPAD / 8) {
        *reinterpret_cast<half8*>(&a_sh[0][t * 8]) = (half8)0;
        *reinterpret_cast<half8*>(&a_sh[1][t * 8]) = (half8)0;
    }

    const float* xrow = x + (size_t)row * NL;

    _Float16 h0c[NFS], h1c[NFS];
#pragma unroll
    for (int k = 0; k < NFS; ++k) {
        h0c[k] = (_Float16)h0[d * NFS + k];
        h1c[k] = (_Float16)h1[d * NFS + k];
    }

    const int l8 = t * 8;
    const int A = CPAD + l8;

    // x window: [l8-32, l8+8) as 5 half8 blocks (zero-clamped at row start)
    const half8 X0 = ldx8z(xrow, l8 - 32);
    const half8 X1 = ldx8z(xrow, l8 - 24);
    const half8 X2 = ldx8z(xrow, l8 - 16);
    const half8 X3 = ldx8z(xrow, l8 - 8);
    const half8 C  = ldx8(xrow + l8);

    const __half2 nlog2e = __float2half2_rn(-1.44269504f);
    const __half2 one2 = __float2half2_rn(1.f);
    const __half2 two2 = __float2half2_rn(2.f);
    __half2 yacc2[4];
#pragma unroll
    for (int p = 0; p < 4; ++p) yacc2[p] = __float2half2_rn(0.f);

#define SH1(L, R) __builtin_shufflevector(L, R, 7, 8, 9, 10, 11, 12, 13, 14)
#define SH2(L, R) __builtin_shufflevector(L, R, 6, 7, 8, 9, 10, 11, 12, 13)
#define SH3(L, R) __builtin_shufflevector(L, R, 5, 6, 7, 8, 9, 10, 11, 12)
#define SH4(L, R) __builtin_shufflevector(L, R, 4, 5, 6, 7, 8, 9, 10, 11)
#define SH6(L, R) __builtin_shufflevector(L, R, 2, 3, 4, 5, 6, 7, 8, 9)
#define CONV_D1(L, R, hc) ((R)*hc[3] + SH1(L, R) * hc[2] + SH2(L, R) * hc[1] + SH3(L, R) * hc[0])
#define CONV_D2(L, R, hc) ((R)*hc[3] + SH2(L, R) * hc[2] + SH4(L, R) * hc[1] + SH6(L, R) * hc[0])

#define GATE(av, bv, SC2)                                           \
    {                                                               \
        __half2 ap_[4], bp_[4];                                     \
        __builtin_memcpy(ap_, &(av), 16);                           \
        __builtin_memcpy(bp_, &(bv), 16);                           \
        _Pragma("unroll") for (int p = 0; p < 4; ++p) {             \
            const __half2 e = h2exp2(__hmul2(ap_[p], nlog2e));      \
            const __half2 s = h2rcp(__hadd2(e, one2));              \
            const __half2 g = __hmul2(__hmul2(s, bp_[p]), SC2);     \
            yacc2[p] = __hadd2(g, yacc2[p]);                        \
        }                                                           \
    }

    // ---- lev 0 (dil=1), register-only
    const half8 a0_1 = CONV_D1(X0, X1, h0c);
    const half8 a0_2 = CONV_D1(X1, X2, h0c);
    const half8 a0_3 = CONV_D1(X2, X3, h0c);
    const half8 a0_4 = CONV_D1(X3, C, h0c);
    const half8 b0 = CONV_D1(X3, C, h1c);

    // ---- lev 1 (dil=2), register-only; gate x2
    const half8 a1_2 = CONV_D2(a0_1, a0_2, h0c);
    const half8 a1_3 = CONV_D2(a0_2, a0_3, h0c);
    const half8 a1_4 = CONV_D2(a0_3, a0_4, h0c);
    const half8 b1 = CONV_D2(a0_3, a0_4, h1c);
    GATE(a1_4, b0, two2)

    // ---- lev 2 (dil=4), register-only; gate
    const half8 s4 = SH4(a1_3, a1_4);
    const half8 s12 = SH4(a1_2, a1_3);
    const half8 a2 = a1_4 * h0c[3] + s4 * h0c[2] + a1_3 * h0c[1] + s12 * h0c[0];
    const half8 b2 = a1_4 * h1c[3] + s4 * h1c[2] + a1_3 * h1c[1] + s12 * h1c[0];
    GATE(a2, b1, one2)

    half8 cur = a2;
    half8 bprev = b2;
    _Float16* rbp = &a_sh[0][0];
    _Float16* wbp = &a_sh[1][0];
    *reinterpret_cast<half8*>(&rbp[A]) = cur;  // publish a2
    __syncthreads();

    half8 an, bn;
#define CMATH(a1v, a2v, a3v)                                              \
    an = cur * h0c[3] + (a1v)*h0c[2] + (a2v)*h0c[1] + (a3v)*h0c[0];       \
    bn = cur * h1c[3] + (a1v)*h1c[2] + (a2v)*h1c[1] + (a3v)*h1c[0];
#define CFIN()                                                            \
    {                                                                     \
        *reinterpret_cast<half8*>(&wbp[A]) = an;                          \
        cur = an;                                                         \
        bprev = bn;                                                       \
        _Float16* tmpp = rbp; rbp = wbp; wbp = tmpp;                      \
    }

    // ---- lev 3..9 (dil=8..512): 3 direct aligned half8 reads, dbuf, 1 barrier/level
    int dil = 8;
#pragma unroll 1
    for (int lev = 3; lev <= 9; ++lev) {
        const half8 a1v = *reinterpret_cast<const half8*>(&rbp[A - dil]);
        const half8 a2v = *reinterpret_cast<const half8*>(&rbp[A - 2 * dil]);
        const half8 a3v = *reinterpret_cast<const half8*>(&rbp[A - 3 * dil]);
        CMATH(a1v, a2v, a3v)
        GATE(an, bprev, one2)
        CFIN()
        dil <<= 1;
        __syncthreads();
    }

    // ---- lev 10 (dil=1024): a-conv only (b_list[10] dead), no write-back
    {
        const half8 a1v = *reinterpret_cast<const half8*>(&rbp[A - 1024]);
        const half8 a2v = *reinterpret_cast<const half8*>(&rbp[A - 2048]);
        const half8 a3v = *reinterpret_cast<const half8*>(&rbp[A - 3072]);
        an = cur * h0c[3] + a1v * h0c[2] + a2v * h0c[1] + a3v * h0c[0];
        GATE(an, bprev, one2)
    }
#undef CMATH
#undef GATE
#undef CFIN
#undef CONV_D1
#undef CONV_D2
#undef SH1
#undef SH2
#undef SH3
#undef SH4
#undef SH6

    const float2 f0 = __half22float2(yacc2[0]);
    const float2 f1 = __half22float2(yacc2[1]);
    const float2 f2 = __half22float2(yacc2[2]);
    const float2 f3 = __half22float2(yacc2[3]);
    uint4 o;
    o.x = pack2bf(f0.x, f0.y);
    o.y = pack2bf(f1.x, f1.y);
    o.z = pack2bf(f2.x, f2.y);
    o.w = pack2bf(f3.x, f3.y);
    *reinterpret_cast<uint4*>(ybf + (size_t)row * NL + t * 8) = o;
}

// ------------------------------------------- K2: y [b][c][l] bf16 -> yT [b][l][c] bf16
// ushort8-vectorized both directions; XOR-swizzled LDS (blk ^= ((row>>3)^row)&7)
// keeps BOTH the b128 writes and the per-column reads bank-conflict-free.
__global__ __launch_bounds__(256) void transpose_kernel(const unsigned short* __restrict__ ybf,
                                                        unsigned short* __restrict__ yT) {
    __shared__ unsigned short tile[64 * 64];
    const int l0 = blockIdx.x * 64;
    const int c0 = blockIdx.y * 64;
    const int b = blockIdx.z;
    const int t = threadIdx.x;

    const int li8 = (t & 7) * 8;   // load: 8 l-cols
    const int ci_ = t >> 3;        // load: c-row (0..31), +32 second pass
#pragma unroll
    for (int p = 0; p < 2; ++p) {
        const int ci = ci_ + p * 32;
        const ushort8 v = *reinterpret_cast<const ushort8*>(
            ybf + (size_t)(b * ND + c0 + ci) * NL + l0 + li8);
        const int blk = ((li8 >> 3) ^ ((ci >> 3) ^ ci)) & 7;
        *reinterpret_cast<ushort8*>(&tile[ci * 64 + blk * 8]) = v;
    }
    __syncthreads();

    const int li_ = t >> 3;        // store: l-row (0..31), +32 second pass
    const int cv8 = (t & 7) * 8;   // store: 8 c-cols
#pragma unroll
    for (int p = 0; p < 2; ++p) {
        const int li = li_ + p * 32;
        ushort8 o;
#pragma unroll
        for (int j = 0; j < 8; ++j) {
            const int r = cv8 + j;
            const int blk = ((li >> 3) ^ ((r >> 3) ^ r)) & 7;
            o[j] = tile[r * 64 + blk * 8 + (li & 7)];
        }
        *reinterpret_cast<ushort8*>(yT + ((size_t)b * NL + l0 + li) * ND + c0 + cv8) = o;
    }
}

// --------------------------- K3: mixed[b][o][l] = bf16( (W @ y)[o][l] + b_mix[o] )
// ring-3 LDS staging, counted vmcnt(4); XCD-chunked block swizzle.
// __launch_bounds__(256,3): cap VGPR so a 3rd block fits per CU (LDS 48KiB allows it)
// -> 12 waves/CU for latency hiding instead of 8.
__global__ __launch_bounds__(256, 3) void gemm_kernel(const unsigned short* __restrict__ wbf,
                                                      const unsigned short* __restrict__ yT,
                                                      const float* __restrict__ bmix,
                                                      unsigned short* __restrict__ mixed) {
    __shared__ unsigned short As[3][BM][BK];  // 24 KiB
    __shared__ unsigned short Bs[3][BN][BK];  // 24 KiB

    // XCD swizzle: 512 blocks, 8 XCDs, 64 per XCD (512%8==0 -> bijective)
    const int orig = blockIdx.x;
    const int wgid = (orig & 7) * 64 + (orig >> 3);
    const int b = wgid & 1;
    const int m0 = ((wgid >> 1) & 7) * BM;
    const int n0 = (wgid >> 4) * BN;

    const int t = threadIdx.x;
    const int lane = t & 63, wid = t >> 6;
    const int wr = wid >> 1, wc = wid & 1;  // 2x2 waves, each 64x64
    const int fr = lane & 15;
    const int fk = (lane >> 4) * 8;

    const int srow = wid * 32 + (lane >> 2);
    const int sk = (lane & 3) * 8;
    const unsigned short* Ag = wbf + (size_t)(m0 + srow) * ND + sk;
    const unsigned short* Bg = yT + ((size_t)b * NL + n0 + srow) * ND + sk;
    unsigned short* A0 = &As[0][0][0];
    unsigned short* B0 = &Bs[0][0][0];
    unsigned short* AsW = A0 + wid * 32 * BK;
    unsigned short* BsW = B0 + wid * 32 * BK;

#define STAGE(bo, kt)                           \
    llds16(Ag + (kt), AsW + (bo));              \
    llds16(Ag + (kt) + 16 * ND, AsW + (bo) + 16 * BK); \
    llds16(Bg + (kt), BsW + (bo));              \
    llds16(Bg + (kt) + 16 * ND, BsW + (bo) + 16 * BK);

    f32x4 acc[4][4];
#pragma unroll
    for (int mi = 0; mi < 4; ++mi)
#pragma unroll
        for (int ni = 0; ni < 4; ++ni)
            acc[mi][ni] = (f32x4){0.f, 0.f, 0.f, 0.f};

    // prologue: stage tiles 0,1 into bufs 0,1 (8 loads outstanding)
    STAGE(0, 0)
    STAGE(ASZ, BK)

    int bc = 0;   // compute buffer index
    int bs = 2;   // stage buffer index
#pragma unroll 1
    for (int ki = 0; ki < NKI; ++ki) {
        if (ki + 1 < NKI) {
            asm volatile("s_waitcnt vmcnt(4)" ::: "memory");  // tile ki landed
        } else {
            asm volatile("s_waitcnt vmcnt(0)" ::: "memory");
        }
        __builtin_amdgcn_s_barrier();
        __builtin_amdgcn_sched_barrier(0);

        if (ki + 2 < NKI) {
            const int bo = bs * ASZ;
            const int kt = (ki + 2) * BK;
            STAGE(bo, kt)
        }

        const int bco = bc * ASZ;
        bf16x8 af[4], bv[4];
#pragma unroll
        for (int mi = 0; mi < 4; ++mi)
            af[mi] = *reinterpret_cast<const bf16x8*>(A0 + bco + (wr * 64 + mi * 16 + fr) * BK + fk);
#pragma unroll
        for (int ni = 0; ni < 4; ++ni)
            bv[ni] = *reinterpret_cast<const bf16x8*>(B0 + bco + (wc * 64 + ni * 16 + fr) * BK + fk);
#pragma unroll
        for (int mi = 0; mi < 4; ++mi)
#pragma unroll
            for (int ni = 0; ni < 4; ++ni)
                acc[mi][ni] = __builtin_amdgcn_mfma_f32_16x16x32_bf16(af[mi], bv[ni],
                                                                      acc[mi][ni], 0, 0, 0);
        bc = (bc == 2) ? 0 : bc + 1;
        bs = (bs == 2) ? 0 : bs + 1;
    }
#undef STAGE

    // epilogue: D[row][col], col = lane&15, row = (lane>>4)*4 + r
    const size_t bbase = (size_t)b * ND * NL;
#pragma unroll
    for (int mi = 0; mi < 4; ++mi) {
#pragma unroll
        for (int r = 0; r < 4; ++r) {
            const int o = m0 + wr * 64 + mi * 16 + (lane >> 4) * 4 + r;
            const float bm = bmix[o];
            const size_t rowbase = bbase + (size_t)o * NL;
#pragma unroll
            for (int ni = 0; ni < 4; ++ni) {
                const int l = n0 + wc * 64 + ni * 16 + fr;
                mixed[rowbase + l] = f2bf(acc[mi][ni][r] + bm);
            }
        }
    }
}

// ------------------------- K4: z = mixed + x (regs) -> LayerNorm over channels -> out
// 1024 threads (16 waves) per block: 32 l-cols x 32 c-groups, zv[32] in registers.
__global__ __launch_bounds__(1024) void ln_kernel(const unsigned short* __restrict__ mixed,
                                                  const float* __restrict__ x,
                                                  const float* __restrict__ gamma,
                                                  const float* __restrict__ beta,
                                                  float* __restrict__ out) {
    __shared__ float gsh[ND], bsh[ND];           // 8 KiB
    __shared__ float sred[32][33], qred[32][33]; // 8.25 KiB
    __shared__ float mu_s[32], rs_s[32];

    const int t = threadIdx.x;
    gsh[t] = gamma[t];
    bsh[t] = beta[t];

    const int b = blockIdx.y;
    const int l0 = blockIdx.x * 32;
    const int tl = t & 31, tg = t >> 5;  // 32 c-groups x 32 cols
    const size_t base = (size_t)b * ND * NL + l0 + tl;

    float zv[32];
    float s = 0.f, q = 0.f;
#pragma unroll
    for (int j = 0; j < 32; ++j) {
        const size_t idx = base + (size_t)(tg + j * 32) * NL;
        const float v = bf2f(mixed[idx]) + x[idx];
        zv[j] = v;
        s += v;
        q += v * v;
    }

    sred[tg][tl] = s;
    qred[tg][tl] = q;
    __syncthreads();  // also covers gsh/bsh writes
    if (tg == 0) {
        float S = 0.f, Q = 0.f;
#pragma unroll
        for (int g = 0; g < 32; ++g) {
            S += sred[g][tl];
            Q += qred[g][tl];
        }
        const float mu = S * (1.f / ND);
        const float var = Q * (1.f / ND) - mu * mu;
        mu_s[tl] = mu;
        rs_s[tl] = rsqrtf(var + LN_EPS);
    }
    __syncthreads();
    const float mu = mu_s[tl], rs = rs_s[tl];
#pragma unroll
    for (int j = 0; j < 32; ++j) {
        const int c = tg + j * 32;
        out[base + (size_t)c * NL] = (zv[j] - mu) * rs * gsh[c] + bsh[c];
    }
}

extern "C" void kernel_launch(void* const* d_in, const int* in_sizes, int n_in,
                              void* d_out, int out_size, void* d_ws, size_t ws_size,
                              hipStream_t stream) {
    (void)in_sizes; (void)n_in; (void)out_size; (void)ws_size;
    const float* x = (const float*)d_in[0];
    const float* h0 = (const float*)d_in[1];
    const float* h1 = (const float*)d_in[2];
    const float* wmix = (const float*)d_in[3];
    const float* bmix = (const float*)d_in[4];
    const float* gamma = (const float*)d_in[5];
    const float* beta = (const float*)d_in[6];
    float* out = (float*)d_out;

    char* ws = (char*)d_ws;
    unsigned short* ybf = (unsigned short*)(ws);                              // 16 MiB
    unsigned short* yT = (unsigned short*)(ws + (size_t)16 * 1024 * 1024);    // 16 MiB
    unsigned short* wbf = (unsigned short*)(ws + (size_t)32 * 1024 * 1024);   // 2 MiB
    unsigned short* mixed = (unsigned short*)(ws + (size_t)34 * 1024 * 1024); // 16 MiB

    wconv_kernel<<<dim3(ND * ND / (256 * 8)), 256, 0, stream>>>(wmix, wbf);
    conv_cascade_kernel<<<dim3(NB * ND), 512, 0, stream>>>(x, h0, h1, ybf);
    transpose_kernel<<<dim3(NL / 64, ND / 64, NB), 256, 0, stream>>>(ybf, yT);
    gemm_kernel<<<dim3(512), 256, 0, stream>>>(wbf, yT, bmix, mixed);
    ln_kernel<<<dim3(NL / 32, NB), 1024, 0, stream>>>(mixed, x, gamma, beta, out);
}

// Round 15
// 93.440 us; speedup vs baseline: 1.0329x; 1.0040x over previous
//
#include <hip/hip_runtime.h>
#include <hip/hip_bf16.h>
#include <hip/hip_fp16.h>

#define NB 2
#define ND 1024
#define NL 4096
#define NFS 4
#define NDEPTH 11
#define LN_EPS 1e-5f

#define BM 128
#define BN 128
#define BK 32
#define NKI (ND / BK)
#define ASZ (BM * BK)  // shorts per A (or B) buffer

#define CPAD 3072          // f16 elements of zero pad (lev10 reads back 3*1024)
#define CBUF (CPAD + NL)   // 7168 f16 = 14336 B per buffer

typedef __bf16 bf16x8 __attribute__((ext_vector_type(8)));
typedef float f32x4 __attribute__((ext_vector_type(4)));
typedef _Float16 half8 __attribute__((ext_vector_type(8)));
typedef unsigned short ushort8 __attribute__((ext_vector_type(8)));

__device__ __forceinline__ unsigned short f2bf(float f) {
    __hip_bfloat16 h = __float2bfloat16(f);
    unsigned short u;
    __builtin_memcpy(&u, &h, 2);
    return u;
}

__device__ __forceinline__ float bf2f(unsigned short u) {
    unsigned int ui = (unsigned int)u << 16;
    float f;
    __builtin_memcpy(&f, &ui, 4);
    return f;
}

__device__ __forceinline__ unsigned int pack2bf(float lo, float hi) {
    return (unsigned int)f2bf(lo) | ((unsigned int)f2bf(hi) << 16);
}

// async global->LDS, 16B per lane (wave-uniform LDS base + lane*16)
__device__ __forceinline__ void llds16(const void* g, void* l) {
    __builtin_amdgcn_global_load_lds(
        (const __attribute__((address_space(1))) unsigned int*)g,
        (__attribute__((address_space(3))) unsigned int*)l, 16, 0, 0);
}

__device__ __forceinline__ half8 ldx8(const float* p) {
    const float4 v0 = *reinterpret_cast<const float4*>(p);
    const float4 v1 = *reinterpret_cast<const float4*>(p + 4);
    half8 r;
    r[0] = (_Float16)v0.x; r[1] = (_Float16)v0.y;
    r[2] = (_Float16)v0.z; r[3] = (_Float16)v0.w;
    r[4] = (_Float16)v1.x; r[5] = (_Float16)v1.y;
    r[6] = (_Float16)v1.z; r[7] = (_Float16)v1.w;
    return r;
}

// zero-clamped block load: valid address always, result zeroed if off<0
__device__ __forceinline__ half8 ldx8z(const float* xrow, int off) {
    half8 v = ldx8(xrow + (off >= 0 ? off : 0));
    return (off >= 0) ? v : (half8)0;
}

// ---------------------------------------------------------------- K0: W -> bf16
__global__ __launch_bounds__(256) void wconv_kernel(const float* __restrict__ w,
                                                    unsigned short* __restrict__ wbf) {
    const int idx8 = (blockIdx.x * 256 + threadIdx.x) * 8;
    const float4 v0 = *reinterpret_cast<const float4*>(w + idx8);
    const float4 v1 = *reinterpret_cast<const float4*>(w + idx8 + 4);
    uint4 o;
    o.x = pack2bf(v0.x, v0.y);
    o.y = pack2bf(v0.z, v0.w);
    o.z = pack2bf(v1.x, v1.y);
    o.w = pack2bf(v1.z, v1.w);
    *reinterpret_cast<uint4*>(wbf + idx8) = o;
}

// ------------------------------------------------- K1: dilated conv cascade + gating
// 256 threads; thread t owns TWO independent 8-elem chains: chunk A = [t*8, t*8+8),
// chunk B = [2048+t*8, 2048+t*8+8) (the two row halves). Doubles the independent
// work per wave between barriers (ILP-hides the barrier round-trip) at ZERO
// redundancy, keeping the conflict-free 16B lane stride. Levels 0-2 register-only
// per chunk; levels 3-9 dbuf LDS (1 barrier/level, ds_write issued BEFORE gates);
// lev 10 a-conv only. Gate fully f16-packed.
__global__ __launch_bounds__(256) void conv_cascade_kernel(const float* __restrict__ x,
                                                           const float* __restrict__ h0,
                                                           const float* __restrict__ h1,
                                                           unsigned short* __restrict__ ybf) {
    __shared__ _Float16 a_sh[2][CBUF];  // 28672 B
    const int row = blockIdx.x;         // b*ND + d
    const int d = row & (ND - 1);
    const int t = threadIdx.x;

    // zero pads: 3072 f16 = 384 half8 chunks per buffer
    *reinterpret_cast<half8*>(&a_sh[0][t * 8]) = (half8)0;
    *reinterpret_cast<half8*>(&a_sh[1][t * 8]) = (half8)0;
    if (t < 128) {
        *reinterpret_cast<half8*>(&a_sh[0][2048 + t * 8]) = (half8)0;
        *reinterpret_cast<half8*>(&a_sh[1][2048 + t * 8]) = (half8)0;
    }

    const float* xrow = x + (size_t)row * NL;

    _Float16 h0c[NFS], h1c[NFS];
#pragma unroll
    for (int k = 0; k < NFS; ++k) {
        h0c[k] = (_Float16)h0[d * NFS + k];
        h1c[k] = (_Float16)h1[d * NFS + k];
    }

    const int lA = t * 8;          // chunk A logical l
    const int lB = 2048 + t * 8;   // chunk B logical l
    const int Aa = CPAD + lA;
    const int Ab = CPAD + lB;

    const __half2 nlog2e = __float2half2_rn(-1.44269504f);
    const __half2 one2 = __float2half2_rn(1.f);
    const __half2 two2 = __float2half2_rn(2.f);
    __half2 yA[4], yB[4];
#pragma unroll
    for (int p = 0; p < 4; ++p) { yA[p] = __float2half2_rn(0.f); yB[p] = __float2half2_rn(0.f); }

#define SH1(L, R) __builtin_shufflevector(L, R, 7, 8, 9, 10, 11, 12, 13, 14)
#define SH2(L, R) __builtin_shufflevector(L, R, 6, 7, 8, 9, 10, 11, 12, 13)
#define SH3(L, R) __builtin_shufflevector(L, R, 5, 6, 7, 8, 9, 10, 11, 12)
#define SH4(L, R) __builtin_shufflevector(L, R, 4, 5, 6, 7, 8, 9, 10, 11)
#define SH6(L, R) __builtin_shufflevector(L, R, 2, 3, 4, 5, 6, 7, 8, 9)
#define CONV_D1(L, R, hc) ((R)*hc[3] + SH1(L, R) * hc[2] + SH2(L, R) * hc[1] + SH3(L, R) * hc[0])
#define CONV_D2(L, R, hc) ((R)*hc[3] + SH2(L, R) * hc[2] + SH4(L, R) * hc[1] + SH6(L, R) * hc[0])

#define GATE(av, bv, yac, SC2)                                      \
    {                                                               \
        __half2 ap_[4], bp_[4];                                     \
        __builtin_memcpy(ap_, &(av), 16);                           \
        __builtin_memcpy(bp_, &(bv), 16);                           \
        _Pragma("unroll") for (int p = 0; p < 4; ++p) {             \
            const __half2 e = h2exp2(__hmul2(ap_[p], nlog2e));      \
            const __half2 s = h2rcp(__hadd2(e, one2));              \
            const __half2 g = __hmul2(__hmul2(s, bp_[p]), SC2);     \
            yac[p] = __hadd2(g, yac[p]);                            \
        }                                                           \
    }

// register-only head (levels 0-2) for one chunk; defines curX/bprevX
#define HEAD(l8, curX, bprevX, yac)                                                  \
    half8 curX, bprevX;                                                              \
    {                                                                                \
        const half8 X0 = ldx8z(xrow, (l8) - 32);                                     \
        const half8 X1 = ldx8z(xrow, (l8) - 24);                                     \
        const half8 X2 = ldx8z(xrow, (l8) - 16);                                     \
        const half8 X3 = ldx8z(xrow, (l8) - 8);                                      \
        const half8 C = ldx8(xrow + (l8));                                           \
        const half8 a0_1 = CONV_D1(X0, X1, h0c);                                     \
        const half8 a0_2 = CONV_D1(X1, X2, h0c);                                     \
        const half8 a0_3 = CONV_D1(X2, X3, h0c);                                     \
        const half8 a0_4 = CONV_D1(X3, C, h0c);                                      \
        const half8 b0 = CONV_D1(X3, C, h1c);                                        \
        const half8 a1_2 = CONV_D2(a0_1, a0_2, h0c);                                 \
        const half8 a1_3 = CONV_D2(a0_2, a0_3, h0c);                                 \
        const half8 a1_4 = CONV_D2(a0_3, a0_4, h0c);                                 \
        const half8 b1 = CONV_D2(a0_3, a0_4, h1c);                                   \
        GATE(a1_4, b0, yac, two2)                                                    \
        const half8 s4 = SH4(a1_3, a1_4);                                            \
        const half8 s12 = SH4(a1_2, a1_3);                                           \
        const half8 a2 = a1_4 * h0c[3] + s4 * h0c[2] + a1_3 * h0c[1] + s12 * h0c[0]; \
        const half8 b2 = a1_4 * h1c[3] + s4 * h1c[2] + a1_3 * h1c[1] + s12 * h1c[0]; \
        GATE(a2, b1, yac, one2)                                                      \
        curX = a2;                                                                   \
        bprevX = b2;                                                                 \
    }

    HEAD(lA, curA, bprevA, yA)
    HEAD(lB, curB, bprevB, yB)
#undef HEAD

    _Float16* rbp = &a_sh[0][0];
    _Float16* wbp = &a_sh[1][0];
    *reinterpret_cast<half8*>(&rbp[Aa]) = curA;  // publish a2 (both chunks)
    *reinterpret_cast<half8*>(&rbp[Ab]) = curB;
    __syncthreads();

    // ---- lev 3..9 (dil=8..512): two independent chains per thread, 1 barrier/level
    int dil = 8;
#pragma unroll 1
    for (int lev = 3; lev <= 9; ++lev) {
        const half8 ta1 = *reinterpret_cast<const half8*>(&rbp[Aa - dil]);
        const half8 ta2 = *reinterpret_cast<const half8*>(&rbp[Aa - 2 * dil]);
        const half8 ta3 = *reinterpret_cast<const half8*>(&rbp[Aa - 3 * dil]);
        const half8 tb1 = *reinterpret_cast<const half8*>(&rbp[Ab - dil]);
        const half8 tb2 = *reinterpret_cast<const half8*>(&rbp[Ab - 2 * dil]);
        const half8 tb3 = *reinterpret_cast<const half8*>(&rbp[Ab - 3 * dil]);
        const half8 anA = curA * h0c[3] + ta1 * h0c[2] + ta2 * h0c[1] + ta3 * h0c[0];
        const half8 anB = curB * h0c[3] + tb1 * h0c[2] + tb2 * h0c[1] + tb3 * h0c[0];
        // write-backs FIRST so they land while the gates compute
        *reinterpret_cast<half8*>(&wbp[Aa]) = anA;
        *reinterpret_cast<half8*>(&wbp[Ab]) = anB;
        const half8 bnA = curA * h1c[3] + ta1 * h1c[2] + ta2 * h1c[1] + ta3 * h1c[0];
        const half8 bnB = curB * h1c[3] + tb1 * h1c[2] + tb2 * h1c[1] + tb3 * h1c[0];
        GATE(anA, bprevA, yA, one2)
        GATE(anB, bprevB, yB, one2)
        curA = anA; bprevA = bnA;
        curB = anB; bprevB = bnB;
        { _Float16* tmpp = rbp; rbp = wbp; wbp = tmpp; }
        dil <<= 1;
        __syncthreads();
    }

    // ---- lev 10 (dil=1024): a-conv only (b_list[10] dead), no write-back.
    //      chunk A taps -2048/-3072 hit the zero pad; chunk B -2048 reads chunk A's
    //      lev-9 value, -3072 hits the pad.
    {
        const half8 ta1 = *reinterpret_cast<const half8*>(&rbp[Aa - 1024]);
        const half8 ta2 = *reinterpret_cast<const half8*>(&rbp[Aa - 2048]);
        const half8 ta3 = *reinterpret_cast<const half8*>(&rbp[Aa - 3072]);
        const half8 anA = curA * h0c[3] + ta1 * h0c[2] + ta2 * h0c[1] + ta3 * h0c[0];
        GATE(anA, bprevA, yA, one2)
        const half8 tb1 = *reinterpret_cast<const half8*>(&rbp[Ab - 1024]);
        const half8 tb2 = *reinterpret_cast<const half8*>(&rbp[Ab - 2048]);
        const half8 tb3 = *reinterpret_cast<const half8*>(&rbp[Ab - 3072]);
        const half8 anB = curB * h0c[3] + tb1 * h0c[2] + tb2 * h0c[1] + tb3 * h0c[0];
        GATE(anB, bprevB, yB, one2)
    }
#undef GATE
#undef CONV_D1
#undef CONV_D2
#undef SH1
#undef SH2
#undef SH3
#undef SH4
#undef SH6

    {
        const float2 f0 = __half22float2(yA[0]);
        const float2 f1 = __half22float2(yA[1]);
        const float2 f2 = __half22float2(yA[2]);
        const float2 f3 = __half22float2(yA[3]);
        uint4 o;
        o.x = pack2bf(f0.x, f0.y);
        o.y = pack2bf(f1.x, f1.y);
        o.z = pack2bf(f2.x, f2.y);
        o.w = pack2bf(f3.x, f3.y);
        *reinterpret_cast<uint4*>(ybf + (size_t)row * NL + lA) = o;
    }
    {
        const float2 f0 = __half22float2(yB[0]);
        const float2 f1 = __half22float2(yB[1]);
        const float2 f2 = __half22float2(yB[2]);
        const float2 f3 = __half22float2(yB[3]);
        uint4 o;
        o.x = pack2bf(f0.x, f0.y);
        o.y = pack2bf(f1.x, f1.y);
        o.z = pack2bf(f2.x, f2.y);
        o.w = pack2bf(f3.x, f3.y);
        *reinterpret_cast<uint4*>(ybf + (size_t)row * NL + lB) = o;
    }
}

// ------------------------------------------- K2: y [b][c][l] bf16 -> yT [b][l][c] bf16
// ushort8-vectorized both directions; XOR-swizzled LDS keeps writes and reads
// bank-conflict-free.
__global__ __launch_bounds__(256) void transpose_kernel(const unsigned short* __restrict__ ybf,
                                                        unsigned short* __restrict__ yT) {
    __shared__ unsigned short tile[64 * 64];
    const int l0 = blockIdx.x * 64;
    const int c0 = blockIdx.y * 64;
    const int b = blockIdx.z;
    const int t = threadIdx.x;

    const int li8 = (t & 7) * 8;   // load: 8 l-cols
    const int ci_ = t >> 3;        // load: c-row (0..31), +32 second pass
#pragma unroll
    for (int p = 0; p < 2; ++p) {
        const int ci = ci_ + p * 32;
        const ushort8 v = *reinterpret_cast<const ushort8*>(
            ybf + (size_t)(b * ND + c0 + ci) * NL + l0 + li8);
        const int blk = ((li8 >> 3) ^ ((ci >> 3) ^ ci)) & 7;
        *reinterpret_cast<ushort8*>(&tile[ci * 64 + blk * 8]) = v;
    }
    __syncthreads();

    const int li_ = t >> 3;        // store: l-row (0..31), +32 second pass
    const int cv8 = (t & 7) * 8;   // store: 8 c-cols
#pragma unroll
    for (int p = 0; p < 2; ++p) {
        const int li = li_ + p * 32;
        ushort8 o;
#pragma unroll
        for (int j = 0; j < 8; ++j) {
            const int r = cv8 + j;
            const int blk = ((li >> 3) ^ ((r >> 3) ^ r)) & 7;
            o[j] = tile[r * 64 + blk * 8 + (li & 7)];
        }
        *reinterpret_cast<ushort8*>(yT + ((size_t)b * NL + l0 + li) * ND + c0 + cv8) = o;
    }
}

// --------------------------- K3: mixed[b][o][l] = bf16( (W @ y)[o][l] + b_mix[o] )
// ring-3 LDS staging, counted vmcnt(4); XCD-chunked block swizzle.
__global__ __launch_bounds__(256) void gemm_kernel(const unsigned short* __restrict__ wbf,
                                                   const unsigned short* __restrict__ yT,
                                                   const float* __restrict__ bmix,
                                                   unsigned short* __restrict__ mixed) {
    __shared__ unsigned short As[3][BM][BK];  // 24 KiB
    __shared__ unsigned short Bs[3][BN][BK];  // 24 KiB

    // XCD swizzle: 512 blocks, 8 XCDs, 64 per XCD (512%8==0 -> bijective)
    const int orig = blockIdx.x;
    const int wgid = (orig & 7) * 64 + (orig >> 3);
    const int b = wgid & 1;
    const int m0 = ((wgid >> 1) & 7) * BM;
    const int n0 = (wgid >> 4) * BN;

    const int t = threadIdx.x;
    const int lane = t & 63, wid = t >> 6;
    const int wr = wid >> 1, wc = wid & 1;  // 2x2 waves, each 64x64
    const int fr = lane & 15;
    const int fk = (lane >> 4) * 8;

    const int srow = wid * 32 + (lane >> 2);
    const int sk = (lane & 3) * 8;
    const unsigned short* Ag = wbf + (size_t)(m0 + srow) * ND + sk;
    const unsigned short* Bg = yT + ((size_t)b * NL + n0 + srow) * ND + sk;
    unsigned short* A0 = &As[0][0][0];
    unsigned short* B0 = &Bs[0][0][0];
    unsigned short* AsW = A0 + wid * 32 * BK;
    unsigned short* BsW = B0 + wid * 32 * BK;

#define STAGE(bo, kt)                           \
    llds16(Ag + (kt), AsW + (bo));              \
    llds16(Ag + (kt) + 16 * ND, AsW + (bo) + 16 * BK); \
    llds16(Bg + (kt), BsW + (bo));              \
    llds16(Bg + (kt) + 16 * ND, BsW + (bo) + 16 * BK);

    f32x4 acc[4][4];
#pragma unroll
    for (int mi = 0; mi < 4; ++mi)
#pragma unroll
        for (int ni = 0; ni < 4; ++ni)
            acc[mi][ni] = (f32x4){0.f, 0.f, 0.f, 0.f};

    // prologue: stage tiles 0,1 into bufs 0,1 (8 loads outstanding)
    STAGE(0, 0)
    STAGE(ASZ, BK)

    int bc = 0;   // compute buffer index
    int bs = 2;   // stage buffer index
#pragma unroll 1
    for (int ki = 0; ki < NKI; ++ki) {
        if (ki + 1 < NKI) {
            asm volatile("s_waitcnt vmcnt(4)" ::: "memory");  // tile ki landed
        } else {
            asm volatile("s_waitcnt vmcnt(0)" ::: "memory");
        }
        __builtin_amdgcn_s_barrier();
        __builtin_amdgcn_sched_barrier(0);

        if (ki + 2 < NKI) {
            const int bo = bs * ASZ;
            const int kt = (ki + 2) * BK;
            STAGE(bo, kt)
        }

        const int bco = bc * ASZ;
        bf16x8 af[4], bv[4];
#pragma unroll
        for (int mi = 0; mi < 4; ++mi)
            af[mi] = *reinterpret_cast<const bf16x8*>(A0 + bco + (wr * 64 + mi * 16 + fr) * BK + fk);
#pragma unroll
        for (int ni = 0; ni < 4; ++ni)
            bv[ni] = *reinterpret_cast<const bf16x8*>(B0 + bco + (wc * 64 + ni * 16 + fr) * BK + fk);
#pragma unroll
        for (int mi = 0; mi < 4; ++mi)
#pragma unroll
            for (int ni = 0; ni < 4; ++ni)
                acc[mi][ni] = __builtin_amdgcn_mfma_f32_16x16x32_bf16(af[mi], bv[ni],
                                                                      acc[mi][ni], 0, 0, 0);
        bc = (bc == 2) ? 0 : bc + 1;
        bs = (bs == 2) ? 0 : bs + 1;
    }
#undef STAGE

    // epilogue: D[row][col], col = lane&15, row = (lane>>4)*4 + r
    const size_t bbase = (size_t)b * ND * NL;
#pragma unroll
    for (int mi = 0; mi < 4; ++mi) {
#pragma unroll
        for (int r = 0; r < 4; ++r) {
            const int o = m0 + wr * 64 + mi * 16 + (lane >> 4) * 4 + r;
            const float bm = bmix[o];
            const size_t rowbase = bbase + (size_t)o * NL;
#pragma unroll
            for (int ni = 0; ni < 4; ++ni) {
                const int l = n0 + wc * 64 + ni * 16 + fr;
                mixed[rowbase + l] = f2bf(acc[mi][ni][r] + bm);
            }
        }
    }
}

// ------------------------- K4: z = mixed + x (regs) -> LayerNorm over channels -> out
// 1024 threads (16 waves) per block: 32 l-cols x 32 c-groups, zv[32] in registers.
__global__ __launch_bounds__(1024) void ln_kernel(const unsigned short* __restrict__ mixed,
                                                  const float* __restrict__ x,
                                                  const float* __restrict__ gamma,
                                                  const float* __restrict__ beta,
                                                  float* __restrict__ out) {
    __shared__ float gsh[ND], bsh[ND];           // 8 KiB
    __shared__ float sred[32][33], qred[32][33]; // 8.25 KiB
    __shared__ float mu_s[32], rs_s[32];

    const int t = threadIdx.x;
    gsh[t] = gamma[t];
    bsh[t] = beta[t];

    const int b = blockIdx.y;
    const int l0 = blockIdx.x * 32;
    const int tl = t & 31, tg = t >> 5;  // 32 c-groups x 32 cols
    const size_t base = (size_t)b * ND * NL + l0 + tl;

    float zv[32];
    float s = 0.f, q = 0.f;
#pragma unroll
    for (int j = 0; j < 32; ++j) {
        const size_t idx = base + (size_t)(tg + j * 32) * NL;
        const float v = bf2f(mixed[idx]) + x[idx];
        zv[j] = v;
        s += v;
        q += v * v;
    }

    sred[tg][tl] = s;
    qred[tg][tl] = q;
    __syncthreads();  // also covers gsh/bsh writes
    if (tg == 0) {
        float S = 0.f, Q = 0.f;
#pragma unroll
        for (int g = 0; g < 32; ++g) {
            S += sred[g][tl];
            Q += qred[g][tl];
        }
        const float mu = S * (1.f / ND);
        const float var = Q * (1.f / ND) - mu * mu;
        mu_s[tl] = mu;
        rs_s[tl] = rsqrtf(var + LN_EPS);
    }
    __syncthreads();
    const float mu = mu_s[tl], rs = rs_s[tl];
#pragma unroll
    for (int j = 0; j < 32; ++j) {
        const int c = tg + j * 32;
        out[base + (size_t)c * NL] = (zv[j] - mu) * rs * gsh[c] + bsh[c];
    }
}

extern "C" void kernel_launch(void* const* d_in, const int* in_sizes, int n_in,
                              void* d_out, int out_size, void* d_ws, size_t ws_size,
                              hipStream_t stream) {
    (void)in_sizes; (void)n_in; (void)out_size; (void)ws_size;
    const float* x = (const float*)d_in[0];
    const float* h0 = (const float*)d_in[1];
    const float* h1 = (const float*)d_in[2];
    const float* wmix = (const float*)d_in[3];
    const float* bmix = (const float*)d_in[4];
    const float* gamma = (const float*)d_in[5];
    const float* beta = (const float*)d_in[6];
    float* out = (float*)d_out;

    char* ws = (char*)d_ws;
    unsigned short* ybf = (unsigned short*)(ws);                              // 16 MiB
    unsigned short* yT = (unsigned short*)(ws + (size_t)16 * 1024 * 1024);    // 16 MiB
    unsigned short* wbf = (unsigned short*)(ws + (size_t)32 * 1024 * 1024);   // 2 MiB
    unsigned short* mixed = (unsigned short*)(ws + (size_t)34 * 1024 * 1024); // 16 MiB

    wconv_kernel<<<dim3(ND * ND / (256 * 8)), 256, 0, stream>>>(wmix, wbf);
    conv_cascade_kernel<<<dim3(NB * ND), 256, 0, stream>>>(x, h0, h1, ybf);
    transpose_kernel<<<dim3(NL / 64, ND / 64, NB), 256, 0, stream>>>(ybf, yT);
    gemm_kernel<<<dim3(512), 256, 0, stream>>>(wbf, yT, bmix, mixed);
    ln_kernel<<<dim3(NL / 32, NB), 1024, 0, stream>>>(mixed, x, gamma, beta, out);
}

// Round 17
// 90.162 us; speedup vs baseline: 1.0705x; 1.0364x over previous
//
#include <hip/hip_runtime.h>
#include <hip/hip_bf16.h>
#include <hip/hip_fp16.h>

#define NB 2
#define ND 1024
#define NL 4096
#define NFS 4
#define NDEPTH 11
#define LN_EPS 1e-5f

#define BM 128
#define BN 128
#define BK 32
#define NKI (ND / BK)
#define ASZ (BM * BK)  // shorts per A (or B) buffer

#define CPAD 3072          // f16 elements of zero pad (lev10 reads back 3*1024)
#define CBUF (CPAD + NL)   // 7168 f16 = 14336 B per buffer

#define CONVGRID (NB * ND)     // row blocks
#define WCONVGRID 128          // W-cast tail blocks: 128 x 512 thr x 16 = ND*ND = 2^20

typedef __bf16 bf16x8 __attribute__((ext_vector_type(8)));
typedef float f32x4 __attribute__((ext_vector_type(4)));
typedef _Float16 half8 __attribute__((ext_vector_type(8)));
typedef unsigned short ushort8 __attribute__((ext_vector_type(8)));

__device__ __forceinline__ unsigned short f2bf(float f) {
    __hip_bfloat16 h = __float2bfloat16(f);
    unsigned short u;
    __builtin_memcpy(&u, &h, 2);
    return u;
}

__device__ __forceinline__ float bf2f(unsigned short u) {
    unsigned int ui = (unsigned int)u << 16;
    float f;
    __builtin_memcpy(&f, &ui, 4);
    return f;
}

__device__ __forceinline__ unsigned int pack2bf(float lo, float hi) {
    return (unsigned int)f2bf(lo) | ((unsigned int)f2bf(hi) << 16);
}

// async global->LDS, 16B per lane (wave-uniform LDS base + lane*16)
__device__ __forceinline__ void llds16(const void* g, void* l) {
    __builtin_amdgcn_global_load_lds(
        (const __attribute__((address_space(1))) unsigned int*)g,
        (__attribute__((address_space(3))) unsigned int*)l, 16, 0, 0);
}

__device__ __forceinline__ half8 ldx8(const float* p) {
    const float4 v0 = *reinterpret_cast<const float4*>(p);
    const float4 v1 = *reinterpret_cast<const float4*>(p + 4);
    half8 r;
    r[0] = (_Float16)v0.x; r[1] = (_Float16)v0.y;
    r[2] = (_Float16)v0.z; r[3] = (_Float16)v0.w;
    r[4] = (_Float16)v1.x; r[5] = (_Float16)v1.y;
    r[6] = (_Float16)v1.z; r[7] = (_Float16)v1.w;
    return r;
}

// zero-clamped block load: valid address always, result zeroed if off<0
__device__ __forceinline__ half8 ldx8z(const float* xrow, int off) {
    half8 v = ldx8(xrow + (off >= 0 ? off : 0));
    return (off >= 0) ? v : (half8)0;
}

// ------------------------------------------------- K1: dilated conv cascade + gating
// (+ W->bf16 cast in tail blocks: no dependency between the two, so they share one
// launch and run concurrently instead of serializing as separate dispatches.)
// Conv: R12-exact structure (best measured 39.5 us). 512 threads; thread t owns
// [t*8, t*8+8) as half8. Levels 0-2 (dil 1/2/4) register-only from a redundant
// x-window; levels 3-9 via double-buffered f16 LDS (1 barrier/level); lev 10
// a-conv only. Gate fully f16-packed (h2exp2/h2rcp).
__global__ __launch_bounds__(512) void conv_cascade_kernel(const float* __restrict__ x,
                                                           const float* __restrict__ h0,
                                                           const float* __restrict__ h1,
                                                           unsigned short* __restrict__ ybf,
                                                           const float* __restrict__ wmix,
                                                           unsigned short* __restrict__ wbf) {
    const int t = threadIdx.x;

    if (blockIdx.x >= CONVGRID) {
        // ---- W -> bf16 tail blocks: 512 threads x 16 floats each
        const int idx16 = ((blockIdx.x - CONVGRID) * 512 + t) * 16;
#pragma unroll
        for (int h = 0; h < 2; ++h) {
            const int idx8 = idx16 + h * 8;
            const float4 v0 = *reinterpret_cast<const float4*>(wmix + idx8);
            const float4 v1 = *reinterpret_cast<const float4*>(wmix + idx8 + 4);
            uint4 o;
            o.x = pack2bf(v0.x, v0.y);
            o.y = pack2bf(v0.z, v0.w);
            o.z = pack2bf(v1.x, v1.y);
            o.w = pack2bf(v1.z, v1.w);
            *reinterpret_cast<uint4*>(wbf + idx8) = o;
        }
        return;
    }

    __shared__ _Float16 a_sh[2][CBUF];  // 28672 B
    const int row = blockIdx.x;         // b*ND + d
    const int d = row & (ND - 1);

    // zero both pads (never written again)
    if (t < CPAD / 8) {
        *reinterpret_cast<half8*>(&a_sh[0][t * 8]) = (half8)0;
        *reinterpret_cast<half8*>(&a_sh[1][t * 8]) = (half8)0;
    }

    const float* xrow = x + (size_t)row * NL;

    _Float16 h0c[NFS], h1c[NFS];
#pragma unroll
    for (int k = 0; k < NFS; ++k) {
        h0c[k] = (_Float16)h0[d * NFS + k];
        h1c[k] = (_Float16)h1[d * NFS + k];
    }

    const int l8 = t * 8;
    const int A = CPAD + l8;

    // x window: [l8-32, l8+8) as 5 half8 blocks (zero-clamped at row start)
    const half8 X0 = ldx8z(xrow, l8 - 32);
    const half8 X1 = ldx8z(xrow, l8 - 24);
    const half8 X2 = ldx8z(xrow, l8 - 16);
    const half8 X3 = ldx8z(xrow, l8 - 8);
    const half8 C  = ldx8(xrow + l8);

    const __half2 nlog2e = __float2half2_rn(-1.44269504f);
    const __half2 one2 = __float2half2_rn(1.f);
    const __half2 two2 = __float2half2_rn(2.f);
    __half2 yacc2[4];
#pragma unroll
    for (int p = 0; p < 4; ++p) yacc2[p] = __float2half2_rn(0.f);

#define SH1(L, R) __builtin_shufflevector(L, R, 7, 8, 9, 10, 11, 12, 13, 14)
#define SH2(L, R) __builtin_shufflevector(L, R, 6, 7, 8, 9, 10, 11, 12, 13)
#define SH3(L, R) __builtin_shufflevector(L, R, 5, 6, 7, 8, 9, 10, 11, 12)
#define SH4(L, R) __builtin_shufflevector(L, R, 4, 5, 6, 7, 8, 9, 10, 11)
#define SH6(L, R) __builtin_shufflevector(L, R, 2, 3, 4, 5, 6, 7, 8, 9)
#define CONV_D1(L, R, hc) ((R)*hc[3] + SH1(L, R) * hc[2] + SH2(L, R) * hc[1] + SH3(L, R) * hc[0])
#define CONV_D2(L, R, hc) ((R)*hc[3] + SH2(L, R) * hc[2] + SH4(L, R) * hc[1] + SH6(L, R) * hc[0])

#define GATE(av, bv, SC2)                                           \
    {                                                               \
        __half2 ap_[4], bp_[4];                                     \
        __builtin_memcpy(ap_, &(av), 16);                           \
        __builtin_memcpy(bp_, &(bv), 16);                           \
        _Pragma("unroll") for (int p = 0; p < 4; ++p) {             \
            const __half2 e = h2exp2(__hmul2(ap_[p], nlog2e));      \
            const __half2 s = h2rcp(__hadd2(e, one2));              \
            const __half2 g = __hmul2(__hmul2(s, bp_[p]), SC2);     \
            yacc2[p] = __hadd2(g, yacc2[p]);                        \
        }                                                           \
    }

    // ---- lev 0 (dil=1), register-only
    const half8 a0_1 = CONV_D1(X0, X1, h0c);
    const half8 a0_2 = CONV_D1(X1, X2, h0c);
    const half8 a0_3 = CONV_D1(X2, X3, h0c);
    const half8 a0_4 = CONV_D1(X3, C, h0c);
    const half8 b0 = CONV_D1(X3, C, h1c);

    // ---- lev 1 (dil=2), register-only; gate x2
    const half8 a1_2 = CONV_D2(a0_1, a0_2, h0c);
    const half8 a1_3 = CONV_D2(a0_2, a0_3, h0c);
    const half8 a1_4 = CONV_D2(a0_3, a0_4, h0c);
    const half8 b1 = CONV_D2(a0_3, a0_4, h1c);
    GATE(a1_4, b0, two2)

    // ---- lev 2 (dil=4), register-only; gate
    const half8 s4 = SH4(a1_3, a1_4);
    const half8 s12 = SH4(a1_2, a1_3);
    const half8 a2 = a1_4 * h0c[3] + s4 * h0c[2] + a1_3 * h0c[1] + s12 * h0c[0];
    const half8 b2 = a1_4 * h1c[3] + s4 * h1c[2] + a1_3 * h1c[1] + s12 * h1c[0];
    GATE(a2, b1, one2)

    half8 cur = a2;
    half8 bprev = b2;
    _Float16* rbp = &a_sh[0][0];
    _Float16* wbp = &a_sh[1][0];
    *reinterpret_cast<half8*>(&rbp[A]) = cur;  // publish a2
    __syncthreads();

    half8 an, bn;
#define CMATH(a1v, a2v, a3v)                                              \
    an = cur * h0c[3] + (a1v)*h0c[2] + (a2v)*h0c[1] + (a3v)*h0c[0];       \
    bn = cur * h1c[3] + (a1v)*h1c[2] + (a2v)*h1c[1] + (a3v)*h1c[0];
#define CFIN()                                                            \
    {                                                                     \
        *reinterpret_cast<half8*>(&wbp[A]) = an;                          \
        cur = an;                                                         \
        bprev = bn;                                                       \
        _Float16* tmpp = rbp; rbp = wbp; wbp = tmpp;                      \
    }

    // ---- lev 3..9 (dil=8..512): 3 direct aligned half8 reads, dbuf, 1 barrier/level
    int dil = 8;
#pragma unroll 1
    for (int lev = 3; lev <= 9; ++lev) {
        const half8 a1v = *reinterpret_cast<const half8*>(&rbp[A - dil]);
        const half8 a2v = *reinterpret_cast<const half8*>(&rbp[A - 2 * dil]);
        const half8 a3v = *reinterpret_cast<const half8*>(&rbp[A - 3 * dil]);
        CMATH(a1v, a2v, a3v)
        GATE(an, bprev, one2)
        CFIN()
        dil <<= 1;
        __syncthreads();
    }

    // ---- lev 10 (dil=1024): a-conv only (b_list[10] dead), no write-back
    {
        const half8 a1v = *reinterpret_cast<const half8*>(&rbp[A - 1024]);
        const half8 a2v = *reinterpret_cast<const half8*>(&rbp[A - 2048]);
        const half8 a3v = *reinterpret_cast<const half8*>(&rbp[A - 3072]);
        an = cur * h0c[3] + a1v * h0c[2] + a2v * h0c[1] + a3v * h0c[0];
        GATE(an, bprev, one2)
    }
#undef CMATH
#undef GATE
#undef CFIN
#undef CONV_D1
#undef CONV_D2
#undef SH1
#undef SH2
#undef SH3
#undef SH4
#undef SH6

    const float2 f0 = __half22float2(yacc2[0]);
    const float2 f1 = __half22float2(yacc2[1]);
    const float2 f2 = __half22float2(yacc2[2]);
    const float2 f3 = __half22float2(yacc2[3]);
    uint4 o;
    o.x = pack2bf(f0.x, f0.y);
    o.y = pack2bf(f1.x, f1.y);
    o.z = pack2bf(f2.x, f2.y);
    o.w = pack2bf(f3.x, f3.y);
    *reinterpret_cast<uint4*>(ybf + (size_t)row * NL + t * 8) = o;
}

// ------------------------------------------- K2: y [b][c][l] bf16 -> yT [b][l][c] bf16
// ushort8-vectorized both directions; XOR-swizzled LDS keeps writes and reads
// bank-conflict-free.
__global__ __launch_bounds__(256) void transpose_kernel(const unsigned short* __restrict__ ybf,
                                                        unsigned short* __restrict__ yT) {
    __shared__ unsigned short tile[64 * 64];
    const int l0 = blockIdx.x * 64;
    const int c0 = blockIdx.y * 64;
    const int b = blockIdx.z;
    const int t = threadIdx.x;

    const int li8 = (t & 7) * 8;   // load: 8 l-cols
    const int ci_ = t >> 3;        // load: c-row (0..31), +32 second pass
#pragma unroll
    for (int p = 0; p < 2; ++p) {
        const int ci = ci_ + p * 32;
        const ushort8 v = *reinterpret_cast<const ushort8*>(
            ybf + (size_t)(b * ND + c0 + ci) * NL + l0 + li8);
        const int blk = ((li8 >> 3) ^ ((ci >> 3) ^ ci)) & 7;
        *reinterpret_cast<ushort8*>(&tile[ci * 64 + blk * 8]) = v;
    }
    __syncthreads();

    const int li_ = t >> 3;        // store: l-row (0..31), +32 second pass
    const int cv8 = (t & 7) * 8;   // store: 8 c-cols
#pragma unroll
    for (int p = 0; p < 2; ++p) {
        const int li = li_ + p * 32;
        ushort8 o;
#pragma unroll
        for (int j = 0; j < 8; ++j) {
            const int r = cv8 + j;
            const int blk = ((li >> 3) ^ ((r >> 3) ^ r)) & 7;
            o[j] = tile[r * 64 + blk * 8 + (li & 7)];
        }
        *reinterpret_cast<ushort8*>(yT + ((size_t)b * NL + l0 + li) * ND + c0 + cv8) = o;
    }
}

// --------------------------- K3: mixed[b][o][l] = bf16( (W @ y)[o][l] + b_mix[o] )
// ring-3 LDS staging, counted vmcnt(4); XCD-chunked block swizzle.
__global__ __launch_bounds__(256) void gemm_kernel(const unsigned short* __restrict__ wbf,
                                                   const unsigned short* __restrict__ yT,
                                                   const float* __restrict__ bmix,
                                                   unsigned short* __restrict__ mixed) {
    __shared__ unsigned short As[3][BM][BK];  // 24 KiB
    __shared__ unsigned short Bs[3][BN][BK];  // 24 KiB

    // XCD swizzle: 512 blocks, 8 XCDs, 64 per XCD (512%8==0 -> bijective)
    const int orig = blockIdx.x;
    const int wgid = (orig & 7) * 64 + (orig >> 3);
    const int b = wgid & 1;
    const int m0 = ((wgid >> 1) & 7) * BM;
    const int n0 = (wgid >> 4) * BN;

    const int t = threadIdx.x;
    const int lane = t & 63, wid = t >> 6;
    const int wr = wid >> 1, wc = wid & 1;  // 2x2 waves, each 64x64
    const int fr = lane & 15;
    const int fk = (lane >> 4) * 8;

    const int srow = wid * 32 + (lane >> 2);
    const int sk = (lane & 3) * 8;
    const unsigned short* Ag = wbf + (size_t)(m0 + srow) * ND + sk;
    const unsigned short* Bg = yT + ((size_t)b * NL + n0 + srow) * ND + sk;
    unsigned short* A0 = &As[0][0][0];
    unsigned short* B0 = &Bs[0][0][0];
    unsigned short* AsW = A0 + wid * 32 * BK;
    unsigned short* BsW = B0 + wid * 32 * BK;

#define STAGE(bo, kt)                           \
    llds16(Ag + (kt), AsW + (bo));              \
    llds16(Ag + (kt) + 16 * ND, AsW + (bo) + 16 * BK); \
    llds16(Bg + (kt), BsW + (bo));              \
    llds16(Bg + (kt) + 16 * ND, BsW + (bo) + 16 * BK);

    f32x4 acc[4][4];
#pragma unroll
    for (int mi = 0; mi < 4; ++mi)
#pragma unroll
        for (int ni = 0; ni < 4; ++ni)
            acc[mi][ni] = (f32x4){0.f, 0.f, 0.f, 0.f};

    // prologue: stage tiles 0,1 into bufs 0,1 (8 loads outstanding)
    STAGE(0, 0)
    STAGE(ASZ, BK)

    int bc = 0;   // compute buffer index
    int bs = 2;   // stage buffer index
#pragma unroll 1
    for (int ki = 0; ki < NKI; ++ki) {
        if (ki + 1 < NKI) {
            asm volatile("s_waitcnt vmcnt(4)" ::: "memory");  // tile ki landed
        } else {
            asm volatile("s_waitcnt vmcnt(0)" ::: "memory");
        }
        __builtin_amdgcn_s_barrier();
        __builtin_amdgcn_sched_barrier(0);

        if (ki + 2 < NKI) {
            const int bo = bs * ASZ;
            const int kt = (ki + 2) * BK;
            STAGE(bo, kt)
        }

        const int bco = bc * ASZ;
        bf16x8 af[4], bv[4];
#pragma unroll
        for (int mi = 0; mi < 4; ++mi)
            af[mi] = *reinterpret_cast<const bf16x8*>(A0 + bco + (wr * 64 + mi * 16 + fr) * BK + fk);
#pragma unroll
        for (int ni = 0; ni < 4; ++ni)
            bv[ni] = *reinterpret_cast<const bf16x8*>(B0 + bco + (wc * 64 + ni * 16 + fr) * BK + fk);
#pragma unroll
        for (int mi = 0; mi < 4; ++mi)
#pragma unroll
            for (int ni = 0; ni < 4; ++ni)
                acc[mi][ni] = __builtin_amdgcn_mfma_f32_16x16x32_bf16(af[mi], bv[ni],
                                                                      acc[mi][ni], 0, 0, 0);
        bc = (bc == 2) ? 0 : bc + 1;
        bs = (bs == 2) ? 0 : bs + 1;
    }
#undef STAGE

    // epilogue: D[row][col], col = lane&15, row = (lane>>4)*4 + r
    const size_t bbase = (size_t)b * ND * NL;
#pragma unroll
    for (int mi = 0; mi < 4; ++mi) {
#pragma unroll
        for (int r = 0; r < 4; ++r) {
            const int o = m0 + wr * 64 + mi * 16 + (lane >> 4) * 4 + r;
            const float bm = bmix[o];
            const size_t rowbase = bbase + (size_t)o * NL;
#pragma unroll
            for (int ni = 0; ni < 4; ++ni) {
                const int l = n0 + wc * 64 + ni * 16 + fr;
                mixed[rowbase + l] = f2bf(acc[mi][ni][r] + bm);
            }
        }
    }
}

// ------------------------- K4: z = mixed + x (regs) -> LayerNorm over channels -> out
// 1024 threads (16 waves) per block: 32 l-cols x 32 c-groups, zv[32] in registers.
__global__ __launch_bounds__(1024) void ln_kernel(const unsigned short* __restrict__ mixed,
                                                  const float* __restrict__ x,
                                                  const float* __restrict__ gamma,
                                                  const float* __restrict__ beta,
                                                  float* __restrict__ out) {
    __shared__ float gsh[ND], bsh[ND];           // 8 KiB
    __shared__ float sred[32][33], qred[32][33]; // 8.25 KiB
    __shared__ float mu_s[32], rs_s[32];

    const int t = threadIdx.x;
    gsh[t] = gamma[t];
    bsh[t] = beta[t];

    const int b = blockIdx.y;
    const int l0 = blockIdx.x * 32;
    const int tl = t & 31, tg = t >> 5;  // 32 c-groups x 32 cols
    const size_t base = (size_t)b * ND * NL + l0 + tl;

    float zv[32];
    float s = 0.f, q = 0.f;
#pragma unroll
    for (int j = 0; j < 32; ++j) {
        const size_t idx = base + (size_t)(tg + j * 32) * NL;
        const float v = bf2f(mixed[idx]) + x[idx];
        zv[j] = v;
        s += v;
        q += v * v;
    }

    sred[tg][tl] = s;
    qred[tg][tl] = q;
    __syncthreads();  // also covers gsh/bsh writes
    if (tg == 0) {
        float S = 0.f, Q = 0.f;
#pragma unroll
        for (int g = 0; g < 32; ++g) {
            S += sred[g][tl];
            Q += qred[g][tl];
        }
        const float mu = S * (1.f / ND);
        const float var = Q * (1.f / ND) - mu * mu;
        mu_s[tl] = mu;
        rs_s[tl] = rsqrtf(var + LN_EPS);
    }
    __syncthreads();
    const float mu = mu_s[tl], rs = rs_s[tl];
#pragma unroll
    for (int j = 0; j < 32; ++j) {
        const int c = tg + j * 32;
        out[base + (size_t)c * NL] = (zv[j] - mu) * rs * gsh[c] + bsh[c];
    }
}

extern "C" void kernel_launch(void* const* d_in, const int* in_sizes, int n_in,
                              void* d_out, int out_size, void* d_ws, size_t ws_size,
                              hipStream_t stream) {
    (void)in_sizes; (void)n_in; (void)out_size; (void)ws_size;
    const float* x = (const float*)d_in[0];
    const float* h0 = (const float*)d_in[1];
    const float* h1 = (const float*)d_in[2];
    const float* wmix = (const float*)d_in[3];
    const float* bmix = (const float*)d_in[4];
    const float* gamma = (const float*)d_in[5];
    const float* beta = (const float*)d_in[6];
    float* out = (float*)d_out;

    char* ws = (char*)d_ws;
    unsigned short* ybf = (unsigned short*)(ws);                              // 16 MiB
    unsigned short* yT = (unsigned short*)(ws + (size_t)16 * 1024 * 1024);    // 16 MiB
    unsigned short* wbf = (unsigned short*)(ws + (size_t)32 * 1024 * 1024);   // 2 MiB
    unsigned short* mixed = (unsigned short*)(ws + (size_t)34 * 1024 * 1024); // 16 MiB

    conv_cascade_kernel<<<dim3(CONVGRID + WCONVGRID), 512, 0, stream>>>(x, h0, h1, ybf,
                                                                        wmix, wbf);
    transpose_kernel<<<dim3(NL / 64, ND / 64, NB), 256, 0, stream>>>(ybf, yT);
    gemm_kernel<<<dim3(512), 256, 0, stream>>>(wbf, yT, bmix, mixed);
    ln_kernel<<<dim3(NL / 32, NB), 1024, 0, stream>>>(mixed, x, gamma, beta, out);
}